// Round 6
// baseline (334.099 us; speedup 1.0000x reference)
//
#include <hip/hip_runtime.h>
#include <stdint.h>

// Problem constants (fixed by the reference's setup_inputs)
#define NB 131072
#define ND 384
#define NA 1024
#define NH 512
#define BM 128     // rows of x per block (4 waves x 32 rows)
#define CAP 256    // sparse correction-pair capacity per block

using bf16x8 = __attribute__((ext_vector_type(8))) __bf16;
using f32x16 = __attribute__((ext_vector_type(16))) float;
using f32x4  = __attribute__((ext_vector_type(4))) float;

__device__ __forceinline__ unsigned short f2bf(float f) {
  unsigned int u = __float_as_uint(f);
  u += 0x7fffu + ((u >> 16) & 1u);   // round-to-nearest-even
  return (unsigned short)(u >> 16);
}

__device__ __forceinline__ void gload_lds16(const void* g, void* l) {
  __builtin_amdgcn_global_load_lds(
      (const __attribute__((address_space(1))) unsigned int*)g,
      (__attribute__((address_space(3))) unsigned int*)l, 16, 0, 0);
}

// ---------------- prep: normalize anchors -> bf16, MFMA B-fragment order for
// v_mfma_f32_32x32x16_bf16: lane l holds an[cb*32+(l&31)][s*16+(l>>5)*8+j].
// Stored so a wave's (cb,s) fragment set is 64 lanes x 16B contiguous.
__global__ void prep_anchors(const float* __restrict__ anchors,
                             short* __restrict__ an_swz) {
  const int a = blockIdx.x;    // anchor row
  const int l = threadIdx.x;   // 64 lanes
  float v[6];
  float ss = 0.f;
#pragma unroll
  for (int e = 0; e < 6; ++e) {
    v[e] = anchors[a * ND + l + 64 * e];
    ss += v[e] * v[e];
  }
#pragma unroll
  for (int off = 32; off >= 1; off >>= 1) ss += __shfl_xor(ss, off);
  const float rn = 1.0f / fmaxf(sqrtf(ss), 1e-12f);
  const int cb = a >> 5;
#pragma unroll
  for (int e = 0; e < 6; ++e) {
    const int k = l + 64 * e;
    const int s = k >> 4, half = (k >> 3) & 1, j = k & 7;
    const int l2 = (a & 31) + 32 * half;
    an_swz[(cb * 24 + s) * 512 + l2 * 8 + j] = (short)f2bf(v[e] * rn);
  }
}

// ---------------- prep: Vsum[h] = sum_a values[a][h] (two-stage, deterministic)
__global__ void vsum_part(const float* __restrict__ values,
                          float* __restrict__ partial) {
  const int jb = blockIdx.x, t = threadIdx.x;
  for (int hh = t; hh < NH; hh += 256) {
    float s = 0.f;
    for (int a2 = 0; a2 < 32; ++a2) s += values[(jb * 32 + a2) * NH + hh];
    partial[jb * NH + hh] = s;
  }
}

__global__ void vsum_final(const float* __restrict__ partial,
                           float* __restrict__ vsum) {
  const int t = threadIdx.x;
  float s = 0.f;
  for (int j = 0; j < 32; ++j) s += partial[j * NH + t];
  vsum[t] = s;
}

// ---------------- main fused kernel
// grid = NB/BM blocks, 256 threads (4 waves, wave w owns rows w*32..+31).
// A-fragments: global -> registers (96 VGPR bf16), no LDS staging for x.
// B: per 32-anchor block (24 KB) cooperatively staged once into dbuf LDS.
// Per cb: stage(next) || 24 MFMA on cur; barrier; quantize+store (regs only,
// so the barrier never waits on qsims store-acks). out written in-block.
__global__ __launch_bounds__(256, 3) void fused_main(
    const float* __restrict__ x, const short* __restrict__ an_swz,
    const float* __restrict__ values, const float* __restrict__ vsum,
    float* __restrict__ out, float* __restrict__ qsims) {
  __shared__ unsigned char bbuf[2][24576];  // B double-buffer (24 KB each)
  __shared__ float denom_add[BM];
  __shared__ int npairs;
  __shared__ int pr_ra[CAP];
  __shared__ float pr_d[CAP];

  const int t = threadIdx.x;
  const int w = t >> 6, l = t & 63;
  const int lc = l & 31, lh = l >> 5;
  const long rowbase = (long)blockIdx.x * BM;
  const int myrow = w * 32 + lc;  // block-local row this lane's A-frags hold

  if (t < BM) denom_add[t] = 0.f;
  if (t == 0) npairs = 0;

  // ---- A fragments: global -> regs (bf16) + row sum-of-squares
  bf16x8 afrag[24];
  float ss = 0.f;
  {
    const float* xrow = x + (rowbase + myrow) * ND + lh * 8;
#pragma unroll
    for (int s = 0; s < 24; ++s) {
      f32x4 v0 = *reinterpret_cast<const f32x4*>(xrow + s * 16);
      f32x4 v1 = *reinterpret_cast<const f32x4*>(xrow + s * 16 + 4);
      ss += v0[0] * v0[0] + v0[1] * v0[1] + v0[2] * v0[2] + v0[3] * v0[3];
      ss += v1[0] * v1[0] + v1[1] * v1[1] + v1[2] * v1[2] + v1[3] * v1[3];
      union { unsigned short us[8]; bf16x8 v; } pk;
#pragma unroll
      for (int e = 0; e < 4; ++e) {
        pk.us[e] = f2bf(v0[e]);
        pk.us[4 + e] = f2bf(v1[e]);
      }
      afrag[s] = pk.v;
    }
  }
  // lanes l and l^32 hold the two k-halves of the same row
  ss += __shfl_xor(ss, 32);
  const float scale = 1.0f / sqrtf((float)ND);
  const float rscale = scale / fmaxf(sqrtf(ss), 1e-12f);

  // per-lane row scales for this lane's 16 C-rows: row=(i&3)+8*(i>>2)+4*lh
  float rs[16];
#pragma unroll
  for (int i = 0; i < 16; ++i)
    rs[i] = __shfl(rscale, (i & 3) + 8 * (i >> 2) + 4 * lh);

  // ---- stage helper: 24 KB of an_swz[cb] -> bbuf[buf], lane-linear
  // (wave w stages bytes {it*4096 + w*1024 + lane*16}, it=0..5)
#define STAGE(cb_, buf_)                                                  \
  {                                                                       \
    const char* _src = (const char*)an_swz + (cb_)*24576 + w * 1024;      \
    unsigned char* _dst = &bbuf[buf_][w * 1024];                          \
    _Pragma("unroll") for (int _it = 0; _it < 6; ++_it)                   \
        gload_lds16(_src + _it * 4096 + l * 16, _dst + _it * 4096);       \
  }

  STAGE(0, 0)
  __syncthreads();

  const long qrow0 = rowbase + w * 32 + 4 * lh;  // + (i&3)+8*(i>>2)
  int cur = 0;
  for (int cb = 0; cb < 32; ++cb) {
    if (cb < 31) STAGE(cb + 1, cur ^ 1)

    f32x16 acc = {0, 0, 0, 0, 0, 0, 0, 0, 0, 0, 0, 0, 0, 0, 0, 0};
    const unsigned char* bp = &bbuf[cur][l * 16];
#pragma unroll
    for (int s = 0; s < 24; ++s) {
      bf16x8 bb = *reinterpret_cast<const bf16x8*>(bp + s * 1024);
      acc = __builtin_amdgcn_mfma_f32_32x32x16_bf16(afrag[s], bb, acc, 0, 0, 0);
    }
    __syncthreads();  // drains stage loads; quantize below is reg-only
    cur ^= 1;

    // quantize + write qsims; C/D: col=lane&31, row=(i&3)+8*(i>>2)+4*(lane>>5)
    const int col = cb * 32 + lc;
    int nz = 0;
#pragma unroll
    for (int i = 0; i < 16; ++i) {
      const float qv = rintf(acc[i] * rs[i] * 20.0f) * 0.05f;
      qsims[(qrow0 + (i & 3) + 8 * (i >> 2)) * NA + col] = qv;
      nz |= (qv != 0.0f) ? 1 : 0;
    }
    if (__ballot(nz != 0)) {  // rare: some sims crossed a bin boundary
#pragma unroll
      for (int i = 0; i < 16; ++i) {
        const float qv = rintf(acc[i] * rs[i] * 20.0f) * 0.05f;
        if (qv != 0.0f) {
          const int rl = w * 32 + 4 * lh + (i & 3) + 8 * (i >> 2);
          const float dl = expf(qv) - 1.0f;
          const int idx = atomicAdd(&npairs, 1);
          if (idx < CAP) {
            pr_ra[idx] = (rl << 10) | col;
            pr_d[idx] = dl;
          }
          atomicAdd(&denom_add[rl], dl);
        }
      }
    }
  }
  __syncthreads();  // pairs/denom final before epilogue

  // ---- epilogue: out rows (vsum tiny + L2-hot; read direct)
  const int np = npairs;
  const int hq = (t & 127) * 4;
  const int rh = t >> 7;
  f32x4 base = *reinterpret_cast<const f32x4*>(&vsum[hq]);
  if (np == 0) {
    const float inv = 1.0f / 1024.0f;
    f32x4 o = {base[0] * inv, base[1] * inv, base[2] * inv, base[3] * inv};
    for (int it = 0; it < 64; ++it) {
      const long r = rowbase + it * 2 + rh;
      *reinterpret_cast<f32x4*>(out + r * NH + hq) = o;
    }
  } else if (np <= CAP) {
    for (int it = 0; it < 64; ++it) {
      const int rl = it * 2 + rh;
      f32x4 o = base;
      float den = 1024.0f;
      for (int p = 0; p < np; ++p) {
        const int ra = pr_ra[p];
        if ((ra >> 10) == rl) {
          const float dl = pr_d[p];
          const float* vrow = values + (ra & 1023) * NH + hq;
          o[0] += dl * vrow[0];
          o[1] += dl * vrow[1];
          o[2] += dl * vrow[2];
          o[3] += dl * vrow[3];
          den += dl;
        }
      }
      const float inv = 1.0f / den;
      o[0] *= inv; o[1] *= inv; o[2] *= inv; o[3] *= inv;
      *reinterpret_cast<f32x4*>(out + (rowbase + rl) * NH + hq) = o;
    }
  } else {
    // fully-general fallback (never expected): recompute from qsims
    for (int it = 0; it < 64; ++it) {
      const long r = rowbase + it * 2 + rh;
      const float* qrow = qsims + r * NA;
      float den = 0.f;
      f32x4 o = {0.f, 0.f, 0.f, 0.f};
      for (int a = 0; a < NA; ++a) {
        const float e = expf(qrow[a]);
        den += e;
        const float* vrow = values + a * NH + hq;
        o[0] += e * vrow[0];
        o[1] += e * vrow[1];
        o[2] += e * vrow[2];
        o[3] += e * vrow[3];
      }
      const float inv = 1.0f / den;
      o[0] *= inv; o[1] *= inv; o[2] *= inv; o[3] *= inv;
      *reinterpret_cast<f32x4*>(out + r * NH + hq) = o;
    }
  }
#undef STAGE
}

extern "C" void kernel_launch(void* const* d_in, const int* in_sizes, int n_in,
                              void* d_out, int out_size, void* d_ws,
                              size_t ws_size, hipStream_t stream) {
  (void)in_sizes; (void)n_in; (void)out_size; (void)ws_size;
  const float* x = (const float*)d_in[0];
  const float* anchors = (const float*)d_in[1];
  const float* values = (const float*)d_in[2];
  float* out = (float*)d_out;                        // [NB, NH]
  float* qsims = out + (size_t)NB * NH;              // [NB, NA]

  // workspace layout
  char* ws = (char*)d_ws;
  short* an_swz = (short*)ws;                        // 768 KB
  float* vsum    = (float*)(ws + 786432);            // 2 KB
  float* partial = (float*)(ws + 786432 + 2048);     // 64 KB

  prep_anchors<<<NA, 64, 0, stream>>>(anchors, an_swz);
  vsum_part<<<32, 256, 0, stream>>>(values, partial);
  vsum_final<<<1, 512, 0, stream>>>(partial, vsum);
  fused_main<<<NB / BM, 256, 0, stream>>>(x, an_swz, values, vsum, out, qsims);
}